// Round 1
// baseline (377.265 us; speedup 1.0000x reference)
//
#include <hip/hip_runtime.h>
#include <hip/hip_bf16.h>

#define N_PTS 1500000
#define CBCH 96
#define CTCH 128
#define COCH 96
#define NB 8
#define BN_EPS 1e-5f

// ws layout (floats)
#define GSUM_OFF 0
#define GSQ_OFF 96
#define SCALE_OFF 192
#define BIAS_OFF 288
#define T_OFF 384   // 8*96 = 768 floats

typedef __attribute__((ext_vector_type(8))) short bf16x8;
typedef __attribute__((ext_vector_type(4))) float f32x4;

__device__ __forceinline__ unsigned short f2bf_rne(float f) {
    union { float f; unsigned u; } v; v.f = f;
    unsigned u = v.u;
    return (unsigned short)((u + 0x7FFFu + ((u >> 16) & 1u)) >> 16);
}

// K0: blocks 0..7 compute T[b][:] = text[b,:] @ W[96:224,:]; block 8 zeroes stats accumulators.
__global__ void k0_init(const float* __restrict__ text, const float* __restrict__ W,
                        float* __restrict__ ws) {
    if (blockIdx.x == NB) {
        for (int i = threadIdx.x; i < 192; i += blockDim.x) ws[i] = 0.f;
        return;
    }
    int b = blockIdx.x;
    int c = threadIdx.x;
    if (c < COCH) {
        float acc = 0.f;
        #pragma unroll 8
        for (int k = 0; k < CTCH; ++k)
            acc += text[b * CTCH + k] * W[(CBCH + k) * COCH + c];
        ws[T_OFF + b * COCH + c] = acc;
    }
}

// K2: finalize per-channel scale/bias from accumulated sums.
__global__ void k2_finalize(const float* __restrict__ gamma, const float* __restrict__ beta,
                            float* __restrict__ ws) {
    int c = threadIdx.x;
    if (c < COCH) {
        float mean = ws[GSUM_OFF + c] * (1.f / (float)N_PTS);
        float var  = ws[GSQ_OFF + c] * (1.f / (float)N_PTS) - mean * mean;
        float scl  = gamma[c] * rsqrtf(var + BN_EPS);
        ws[SCALE_OFF + c] = scl;
        ws[BIAS_OFF + c]  = beta[c] - mean * scl;
    }
}

// Shared GEMM helpers -------------------------------------------------------
// Wave computes 16 points x 96 channels per tile.
// MFMA 16x16x32 bf16: A lane(l): row=l&15, k=8*(l>>4)+j ; B lane: col=l&15, k=8*(l>>4)+j
// D lane: col=l&15, row=4*(l>>4)+reg

__device__ __forceinline__ void load_bfrag(const float* __restrict__ W, int grp, int lr,
                                           bf16x8 bf[6][3]) {
    #pragma unroll
    for (int ct = 0; ct < 6; ++ct)
        #pragma unroll
        for (int kt = 0; kt < 3; ++kt)
            #pragma unroll
            for (int j = 0; j < 8; ++j)
                bf[ct][kt][j] = (short)f2bf_rne(W[(kt * 32 + grp * 8 + j) * COCH + ct * 16 + lr]);
}

__device__ __forceinline__ void tile_gemm(const float* __restrict__ bb,
                                          const int* __restrict__ bidx,
                                          const float* __restrict__ sT,
                                          int base, int grp, int lr,
                                          const bf16x8 bf[6][3], f32x4 acc[6]) {
    // init accumulators with T[batch_idx] (the text-feature half of the GEMM)
    #pragma unroll
    for (int r = 0; r < 4; ++r) {
        int b = bidx[base + grp * 4 + r];
        #pragma unroll
        for (int ct = 0; ct < 6; ++ct)
            acc[ct][r] = sT[b * COCH + ct * 16 + lr];
    }
    // A fragments: 8 consecutive channels of this lane's point
    bf16x8 af[3];
    #pragma unroll
    for (int kt = 0; kt < 3; ++kt) {
        const float4* p = reinterpret_cast<const float4*>(bb + (size_t)(base + lr) * CBCH + kt * 32 + grp * 8);
        float4 x0 = p[0], x1 = p[1];
        af[kt][0] = (short)f2bf_rne(x0.x); af[kt][1] = (short)f2bf_rne(x0.y);
        af[kt][2] = (short)f2bf_rne(x0.z); af[kt][3] = (short)f2bf_rne(x0.w);
        af[kt][4] = (short)f2bf_rne(x1.x); af[kt][5] = (short)f2bf_rne(x1.y);
        af[kt][6] = (short)f2bf_rne(x1.z); af[kt][7] = (short)f2bf_rne(x1.w);
    }
    #pragma unroll
    for (int ct = 0; ct < 6; ++ct)
        #pragma unroll
        for (int kt = 0; kt < 3; ++kt)
            acc[ct] = __builtin_amdgcn_mfma_f32_16x16x32_bf16(af[kt], bf[ct][kt], acc[ct], 0, 0, 0);
}

// K1: stats pass — compute x, accumulate per-channel sum & sumsq, discard x.
__global__ __launch_bounds__(256, 2) void k1_stats(const float* __restrict__ bb,
                                                   const int* __restrict__ bidx,
                                                   const float* __restrict__ W,
                                                   float* __restrict__ ws) {
    __shared__ float sT[NB * COCH];
    __shared__ float sred[2][4][COCH];
    for (int i = threadIdx.x; i < NB * COCH; i += blockDim.x) sT[i] = ws[T_OFF + i];
    __syncthreads();

    const int lane = threadIdx.x & 63;
    const int wv = threadIdx.x >> 6;
    const int grp = lane >> 4, lr = lane & 15;

    bf16x8 bf[6][3];
    load_bfrag(W, grp, lr, bf);

    float sum[6] = {0.f, 0.f, 0.f, 0.f, 0.f, 0.f};
    float sq[6] = {0.f, 0.f, 0.f, 0.f, 0.f, 0.f};

    const int gw = blockIdx.x * 4 + wv;
    const int nw = gridDim.x * 4;
    const int NT = N_PTS / 16;
    for (int t = gw; t < NT; t += nw) {
        int base = t * 16;
        f32x4 acc[6];
        tile_gemm(bb, bidx, sT, base, grp, lr, bf, acc);
        #pragma unroll
        for (int ct = 0; ct < 6; ++ct)
            #pragma unroll
            for (int r = 0; r < 4; ++r) {
                float x = acc[ct][r];
                sum[ct] += x;
                sq[ct] += x * x;
            }
    }

    // cross-lane: reduce over the 4 row-groups (lanes sharing col lr)
    #pragma unroll
    for (int ct = 0; ct < 6; ++ct) {
        float s = sum[ct], q = sq[ct];
        s += __shfl_xor(s, 16); q += __shfl_xor(q, 16);
        s += __shfl_xor(s, 32); q += __shfl_xor(q, 32);
        if (lane < 16) {
            sred[0][wv][ct * 16 + lane] = s;
            sred[1][wv][ct * 16 + lane] = q;
        }
    }
    __syncthreads();
    if (threadIdx.x < COCH) {
        int c = threadIdx.x;
        float s = sred[0][0][c] + sred[0][1][c] + sred[0][2][c] + sred[0][3][c];
        float q = sred[1][0][c] + sred[1][1][c] + sred[1][2][c] + sred[1][3][c];
        atomicAdd(&ws[GSUM_OFF + c], s);
        atomicAdd(&ws[GSQ_OFF + c], q);
    }
}

// K3: output pass — recompute x, apply BN scale/bias + ReLU, store.
__global__ __launch_bounds__(256, 2) void k3_out(const float* __restrict__ bb,
                                                 const int* __restrict__ bidx,
                                                 const float* __restrict__ W,
                                                 const float* __restrict__ ws,
                                                 float* __restrict__ out) {
    __shared__ float sT[NB * COCH];
    for (int i = threadIdx.x; i < NB * COCH; i += blockDim.x) sT[i] = ws[T_OFF + i];
    __syncthreads();

    const int lane = threadIdx.x & 63;
    const int wv = threadIdx.x >> 6;
    const int grp = lane >> 4, lr = lane & 15;

    bf16x8 bf[6][3];
    load_bfrag(W, grp, lr, bf);

    float sc[6], bs[6];
    #pragma unroll
    for (int ct = 0; ct < 6; ++ct) {
        sc[ct] = ws[SCALE_OFF + ct * 16 + lr];
        bs[ct] = ws[BIAS_OFF + ct * 16 + lr];
    }

    const int gw = blockIdx.x * 4 + wv;
    const int nw = gridDim.x * 4;
    const int NT = N_PTS / 16;
    for (int t = gw; t < NT; t += nw) {
        int base = t * 16;
        f32x4 acc[6];
        tile_gemm(bb, bidx, sT, base, grp, lr, bf, acc);
        #pragma unroll
        for (int ct = 0; ct < 6; ++ct)
            #pragma unroll
            for (int r = 0; r < 4; ++r) {
                float y = fmaxf(acc[ct][r] * sc[ct] + bs[ct], 0.f);
                out[(size_t)(base + grp * 4 + r) * COCH + ct * 16 + lr] = y;
            }
    }
}

extern "C" void kernel_launch(void* const* d_in, const int* in_sizes, int n_in,
                              void* d_out, int out_size, void* d_ws, size_t ws_size,
                              hipStream_t stream) {
    const float* bb    = (const float*)d_in[0];
    const int*   bidx  = (const int*)d_in[1];
    const float* text  = (const float*)d_in[2];
    const float* W     = (const float*)d_in[3];
    const float* gamma = (const float*)d_in[4];
    const float* beta  = (const float*)d_in[5];
    float* out = (float*)d_out;
    float* ws  = (float*)d_ws;

    hipLaunchKernelGGL(k0_init, dim3(NB + 1), dim3(128), 0, stream, text, W, ws);
    hipLaunchKernelGGL(k1_stats, dim3(2048), dim3(256), 0, stream, bb, bidx, W, ws);
    hipLaunchKernelGGL(k2_finalize, dim3(1), dim3(128), 0, stream, gamma, beta, ws);
    hipLaunchKernelGGL(k3_out, dim3(2048), dim3(256), 0, stream, bb, bidx, W, ws, out);
}

// Round 2
// 376.438 us; speedup vs baseline: 1.0022x; 1.0022x over previous
//
#include <hip/hip_runtime.h>
#include <hip/hip_bf16.h>

#define N_PTS 1500000
#define CBCH 96
#define CTCH 128
#define COCH 96
#define NB 8
#define BN_EPS 1e-5f

// ws layout (floats)
#define GSUM_OFF 0
#define GSQ_OFF 96
#define T_OFF 384   // 8*96 = 768 floats

typedef __attribute__((ext_vector_type(8))) short bf16x8;
typedef __attribute__((ext_vector_type(4))) float f32x4;

__device__ __forceinline__ unsigned short f2bf_rne(float f) {
    union { float f; unsigned u; } v; v.f = f;
    unsigned u = v.u;
    return (unsigned short)((u + 0x7FFFu + ((u >> 16) & 1u)) >> 16);
}

// K0: blocks 0..7 compute T[b][:] = text[b,:] @ W[96:224,:]; block 8 zeroes stats accumulators.
__global__ void k0_init(const float* __restrict__ text, const float* __restrict__ W,
                        float* __restrict__ ws) {
    if (blockIdx.x == NB) {
        for (int i = threadIdx.x; i < 192; i += blockDim.x) ws[i] = 0.f;
        return;
    }
    int b = blockIdx.x;
    int c = threadIdx.x;
    if (c < COCH) {
        float acc = 0.f;
        #pragma unroll 8
        for (int k = 0; k < CTCH; ++k)
            acc += text[b * CTCH + k] * W[(CBCH + k) * COCH + c];
        ws[T_OFF + b * COCH + c] = acc;
    }
}

// Shared helpers ------------------------------------------------------------
// MFMA 16x16x32 bf16 mapping: A lane(l): row=l&15, k=8*(l>>4)+j ;
// B lane(l): col=l&15, k=8*(l>>4)+j ; D lane(l): col=l&15, row=4*(l>>4)+reg

__device__ __forceinline__ void load_bfrag(const float* __restrict__ W, int grp, int lr,
                                           bf16x8 bf[6][3]) {
    // bf[ct][kt]: lane holds W[k = kt*32 + grp*8 + j][channel = ct*16 + lr]
    #pragma unroll
    for (int ct = 0; ct < 6; ++ct)
        #pragma unroll
        for (int kt = 0; kt < 3; ++kt)
            #pragma unroll
            for (int j = 0; j < 8; ++j)
                bf[ct][kt][j] = (short)f2bf_rne(W[(kt * 32 + grp * 8 + j) * COCH + ct * 16 + lr]);
}

// K1: stats pass — compute x, accumulate per-channel sum & sumsq, discard x.
// (unchanged from the passing version; forward order populates L3 with backbone tail)
__global__ __launch_bounds__(256, 2) void k1_stats(const float* __restrict__ bb,
                                                   const int* __restrict__ bidx,
                                                   const float* __restrict__ W,
                                                   float* __restrict__ ws) {
    __shared__ float sT[NB * COCH];
    __shared__ float sred[2][4][COCH];
    for (int i = threadIdx.x; i < NB * COCH; i += blockDim.x) sT[i] = ws[T_OFF + i];
    __syncthreads();

    const int lane = threadIdx.x & 63;
    const int wv = threadIdx.x >> 6;
    const int grp = lane >> 4, lr = lane & 15;

    bf16x8 bf[6][3];
    load_bfrag(W, grp, lr, bf);

    float sum[6] = {0.f, 0.f, 0.f, 0.f, 0.f, 0.f};
    float sq[6] = {0.f, 0.f, 0.f, 0.f, 0.f, 0.f};

    const int gw = blockIdx.x * 4 + wv;
    const int nw = gridDim.x * 4;
    const int NT = N_PTS / 16;
    for (int t = gw; t < NT; t += nw) {
        int base = t * 16;
        f32x4 acc[6];
        // acc init with T[batch_idx]: D col=channel=lr here (unswapped), row=point
        #pragma unroll
        for (int r = 0; r < 4; ++r) {
            int b = bidx[base + grp * 4 + r];
            #pragma unroll
            for (int ct = 0; ct < 6; ++ct)
                acc[ct][r] = sT[b * COCH + ct * 16 + lr];
        }
        bf16x8 af[3];
        #pragma unroll
        for (int kt = 0; kt < 3; ++kt) {
            const f32x4* p = reinterpret_cast<const f32x4*>(bb + (size_t)(base + lr) * CBCH + kt * 32 + grp * 8);
            f32x4 x0 = p[0], x1 = p[1];
            #pragma unroll
            for (int j = 0; j < 4; ++j) {
                af[kt][j]     = (short)f2bf_rne(x0[j]);
                af[kt][4 + j] = (short)f2bf_rne(x1[j]);
            }
        }
        #pragma unroll
        for (int ct = 0; ct < 6; ++ct)
            #pragma unroll
            for (int kt = 0; kt < 3; ++kt)
                acc[ct] = __builtin_amdgcn_mfma_f32_16x16x32_bf16(af[kt], bf[ct][kt], acc[ct], 0, 0, 0);
        #pragma unroll
        for (int ct = 0; ct < 6; ++ct)
            #pragma unroll
            for (int r = 0; r < 4; ++r) {
                float x = acc[ct][r];
                sum[ct] += x;
                sq[ct] += x * x;
            }
    }

    #pragma unroll
    for (int ct = 0; ct < 6; ++ct) {
        float s = sum[ct], q = sq[ct];
        s += __shfl_xor(s, 16); q += __shfl_xor(q, 16);
        s += __shfl_xor(s, 32); q += __shfl_xor(q, 32);
        if (lane < 16) {
            sred[0][wv][ct * 16 + lane] = s;
            sred[1][wv][ct * 16 + lane] = q;
        }
    }
    __syncthreads();
    if (threadIdx.x < COCH) {
        int c = threadIdx.x;
        float s = sred[0][0][c] + sred[0][1][c] + sred[0][2][c] + sred[0][3][c];
        float q = sred[1][0][c] + sred[1][1][c] + sred[1][2][c] + sred[1][3][c];
        atomicAdd(&ws[GSUM_OFF + c], s);
        atomicAdd(&ws[GSQ_OFF + c], q);
    }
}

// K3: output pass — SWAPPED operands (D: col=point, row=channel) so each lane
// holds 4 consecutive channels of one point -> float4 stores. Reverse tile
// order to hit the backbone tail that k1 left in L3; non-temporal stores keep
// the write stream from evicting it.
__global__ __launch_bounds__(256, 2) void k3_out(const float* __restrict__ bb,
                                                 const int* __restrict__ bidx,
                                                 const float* __restrict__ W,
                                                 const float* __restrict__ gamma,
                                                 const float* __restrict__ beta,
                                                 const float* __restrict__ ws,
                                                 float* __restrict__ out) {
    __shared__ float sT[NB * COCH];
    __shared__ float sScale[COCH];
    __shared__ float sBias[COCH];
    for (int i = threadIdx.x; i < NB * COCH; i += blockDim.x) sT[i] = ws[T_OFF + i];
    if (threadIdx.x < COCH) {
        int c = threadIdx.x;
        float mean = ws[GSUM_OFF + c] * (1.f / (float)N_PTS);
        float var  = ws[GSQ_OFF + c] * (1.f / (float)N_PTS) - mean * mean;
        float scl  = gamma[c] * rsqrtf(var + BN_EPS);
        sScale[c] = scl;
        sBias[c]  = beta[c] - mean * scl;
    }
    __syncthreads();

    const int lane = threadIdx.x & 63;
    const int wv = threadIdx.x >> 6;
    const int grp = lane >> 4, lr = lane & 15;

    bf16x8 bf[6][3];
    load_bfrag(W, grp, lr, bf);

    // per-lane scale/bias: channel = ct*16 + grp*4 + r (consecutive in r)
    f32x4 sc[6], bs[6];
    #pragma unroll
    for (int ct = 0; ct < 6; ++ct) {
        sc[ct] = *reinterpret_cast<const f32x4*>(&sScale[ct * 16 + grp * 4]);
        bs[ct] = *reinterpret_cast<const f32x4*>(&sBias[ct * 16 + grp * 4]);
    }

    const int gw = blockIdx.x * 4 + wv;
    const int nw = gridDim.x * 4;
    const int NT = N_PTS / 16;
    for (int t = NT - 1 - gw; t >= 0; t -= nw) {
        int base = t * 16;
        int b = bidx[base + lr];   // this lane's point's batch
        f32x4 acc[6];
        #pragma unroll
        for (int ct = 0; ct < 6; ++ct)
            acc[ct] = *reinterpret_cast<const f32x4*>(&sT[b * COCH + ct * 16 + grp * 4]);

        // point fragment (B operand): lane's point = base+lr, k = kt*32+grp*8+j
        bf16x8 pf[3];
        #pragma unroll
        for (int kt = 0; kt < 3; ++kt) {
            const f32x4* p = reinterpret_cast<const f32x4*>(bb + (size_t)(base + lr) * CBCH + kt * 32 + grp * 8);
            f32x4 x0 = __builtin_nontemporal_load(p);
            f32x4 x1 = __builtin_nontemporal_load(p + 1);
            #pragma unroll
            for (int j = 0; j < 4; ++j) {
                pf[kt][j]     = (short)f2bf_rne(x0[j]);
                pf[kt][4 + j] = (short)f2bf_rne(x1[j]);
            }
        }
        #pragma unroll
        for (int ct = 0; ct < 6; ++ct)
            #pragma unroll
            for (int kt = 0; kt < 3; ++kt)
                acc[ct] = __builtin_amdgcn_mfma_f32_16x16x32_bf16(bf[ct][kt], pf[kt], acc[ct], 0, 0, 0);

        #pragma unroll
        for (int ct = 0; ct < 6; ++ct) {
            f32x4 y;
            #pragma unroll
            for (int r = 0; r < 4; ++r)
                y[r] = fmaxf(acc[ct][r] * sc[ct][r] + bs[ct][r], 0.f);
            __builtin_nontemporal_store(y,
                reinterpret_cast<f32x4*>(out + (size_t)(base + lr) * COCH + ct * 16 + grp * 4));
        }
    }
}

extern "C" void kernel_launch(void* const* d_in, const int* in_sizes, int n_in,
                              void* d_out, int out_size, void* d_ws, size_t ws_size,
                              hipStream_t stream) {
    const float* bb    = (const float*)d_in[0];
    const int*   bidx  = (const int*)d_in[1];
    const float* text  = (const float*)d_in[2];
    const float* W     = (const float*)d_in[3];
    const float* gamma = (const float*)d_in[4];
    const float* beta  = (const float*)d_in[5];
    float* out = (float*)d_out;
    float* ws  = (float*)d_ws;

    hipLaunchKernelGGL(k0_init, dim3(NB + 1), dim3(128), 0, stream, text, W, ws);
    hipLaunchKernelGGL(k1_stats, dim3(2048), dim3(256), 0, stream, bb, bidx, W, ws);
    hipLaunchKernelGGL(k3_out, dim3(2048), dim3(256), 0, stream, bb, bidx, W, gamma, beta, ws, out);
}

// Round 3
// 369.298 us; speedup vs baseline: 1.0216x; 1.0193x over previous
//
#include <hip/hip_runtime.h>
#include <hip/hip_bf16.h>

#define N_PTS 1500000
#define NT_TILES (N_PTS / 16)   // 93750, exact
#define CBCH 96
#define CTCH 128
#define COCH 96
#define NB 8
#define BN_EPS 1e-5f
#define GRID1 512
#define STPAD 100               // sT row stride (floats): 100%32=4 -> spreads banks, 400B keeps 16B align

// ws float offsets
#define GSUM_OFF 0
#define GSQ_OFF 96
#define T_OFF 384   // 8*96 floats

typedef __attribute__((ext_vector_type(8))) short bf16x8;
typedef __attribute__((ext_vector_type(4))) float f32x4;

__device__ __forceinline__ short f2bf(float f) {
    __hip_bfloat16 h = __float2bfloat16(f);   // native v_cvt path on gfx950, RNE
    short s;
    __builtin_memcpy(&s, &h, sizeof(s));
    return s;
}

// K0: blocks 0..7 compute T[b][:] = text[b,:] @ W[96:224,:]; block 8 zeroes stats accumulators.
__global__ void k0_init(const float* __restrict__ text, const float* __restrict__ W,
                        float* __restrict__ ws) {
    if (blockIdx.x == NB) {
        for (int i = threadIdx.x; i < 192; i += blockDim.x) ws[i] = 0.f;
        return;
    }
    int b = blockIdx.x;
    int c = threadIdx.x;
    if (c < COCH) {
        float acc = 0.f;
        #pragma unroll 8
        for (int k = 0; k < CTCH; ++k)
            acc += text[b * CTCH + k] * W[(CBCH + k) * COCH + c];
        ws[T_OFF + b * COCH + c] = acc;
    }
}

// ---------------------------------------------------------------------------
// MFMA 16x16x32 bf16 mapping: A lane(l): row=l&15, k=8*(l>>4)+j ;
// B lane(l): col=l&15, k=8*(l>>4)+j ; D lane(l): col=l&15, row=4*(l>>4)+reg
// Swapped form everywhere: A = W^T fragment (row=channel), B = points (col=point).
// Lane (grp=l>>4, lr=l&15) output: channel ct*16+grp*4+r of point base+lr.

// Stage W (backbone rows, bf16) into LDS pre-swizzled so each lane's fragment
// (ct,kt) is one aligned 16B chunk: layout [ct][kt][lane][j].
__device__ __forceinline__ void stage_W(const float* __restrict__ W, short* sW) {
    for (int i = threadIdx.x; i < CBCH * COCH; i += blockDim.x) {
        int k = i / COCH, c = i % COCH;               // W[k][c], coalesced read
        int ct = c >> 4, lr = c & 15;
        int kt = k >> 5, grp = (k >> 3) & 3, j = k & 7;
        sW[(((ct * 3 + kt) * 64) + (grp * 16 + lr)) * 8 + j] = f2bf(W[i]);
    }
}

__device__ __forceinline__ void load_bfrag_lds(const short* sW, int lane, bf16x8 bf[6][3]) {
    #pragma unroll
    for (int ct = 0; ct < 6; ++ct)
        #pragma unroll
        for (int kt = 0; kt < 3; ++kt)
            bf[ct][kt] = *reinterpret_cast<const bf16x8*>(sW + ((ct * 3 + kt) * 64 + lane) * 8);
}

// One 16-point tile: gather T[bidx] into acc, convert point features, MFMA.
__device__ __forceinline__ void tile_acc(const float* __restrict__ bb,
                                         const int* __restrict__ bidx,
                                         const float* __restrict__ sT,
                                         const bf16x8 bf[6][3],
                                         int base, int grp, int lr,
                                         f32x4 acc[6]) {
    int b = bidx[base + lr];
    #pragma unroll
    for (int ct = 0; ct < 6; ++ct)
        acc[ct] = *reinterpret_cast<const f32x4*>(&sT[b * STPAD + ct * 16 + grp * 4]);

    bf16x8 pf[3];
    #pragma unroll
    for (int kt = 0; kt < 3; ++kt) {
        const f32x4* p = reinterpret_cast<const f32x4*>(bb + (size_t)(base + lr) * CBCH + kt * 32 + grp * 8);
        f32x4 x0 = p[0], x1 = p[1];
        #pragma unroll
        for (int j = 0; j < 4; ++j) {
            pf[kt][j]     = f2bf(x0[j]);
            pf[kt][4 + j] = f2bf(x1[j]);
        }
    }
    #pragma unroll
    for (int ct = 0; ct < 6; ++ct)
        #pragma unroll
        for (int kt = 0; kt < 3; ++kt)
            acc[ct] = __builtin_amdgcn_mfma_f32_16x16x32_bf16(bf[ct][kt], pf[kt], acc[ct], 0, 0, 0);
}

// K1: stats pass — compute x, accumulate per-channel sum & sumsq, discard x.
__global__ __launch_bounds__(256, 2) void k1_stats(const float* __restrict__ bb,
                                                   const int* __restrict__ bidx,
                                                   const float* __restrict__ W,
                                                   float* __restrict__ ws) {
    __shared__ __align__(16) short sW[6 * 3 * 64 * 8];
    __shared__ __align__(16) float sT[NB * STPAD];
    __shared__ float sredS[4][COCH];
    __shared__ float sredQ[4][COCH];

    stage_W(W, sW);
    for (int i = threadIdx.x; i < NB * COCH; i += blockDim.x)
        sT[(i / COCH) * STPAD + (i % COCH)] = ws[T_OFF + i];
    __syncthreads();

    const int lane = threadIdx.x & 63;
    const int wv = threadIdx.x >> 6;
    const int grp = lane >> 4, lr = lane & 15;

    bf16x8 bf[6][3];
    load_bfrag_lds(sW, lane, bf);

    f32x4 sum[6], sq[6];
    #pragma unroll
    for (int ct = 0; ct < 6; ++ct) { sum[ct] = (f32x4)0.f; sq[ct] = (f32x4)0.f; }

    const int gw = blockIdx.x * 4 + wv;
    for (int t = gw; t < NT_TILES; t += GRID1 * 4) {
        int base = t * 16;
        f32x4 acc[6];
        tile_acc(bb, bidx, sT, bf, base, grp, lr, acc);
        #pragma unroll
        for (int ct = 0; ct < 6; ++ct) {
            sum[ct] += acc[ct];
            sq[ct] += acc[ct] * acc[ct];
        }
    }

    // reduce over lr (16 lanes of same grp hold same channels, different points)
    #pragma unroll
    for (int ct = 0; ct < 6; ++ct)
        #pragma unroll
        for (int r = 0; r < 4; ++r) {
            float s = sum[ct][r], q = sq[ct][r];
            s += __shfl_xor(s, 1);  q += __shfl_xor(q, 1);
            s += __shfl_xor(s, 2);  q += __shfl_xor(q, 2);
            s += __shfl_xor(s, 4);  q += __shfl_xor(q, 4);
            s += __shfl_xor(s, 8);  q += __shfl_xor(q, 8);
            if (lr == 0) {
                sredS[wv][ct * 16 + grp * 4 + r] = s;
                sredQ[wv][ct * 16 + grp * 4 + r] = q;
            }
        }
    __syncthreads();
    if (threadIdx.x < COCH) {
        int c = threadIdx.x;
        atomicAdd(&ws[GSUM_OFF + c], sredS[0][c] + sredS[1][c] + sredS[2][c] + sredS[3][c]);
        atomicAdd(&ws[GSQ_OFF + c],  sredQ[0][c] + sredQ[1][c] + sredQ[2][c] + sredQ[3][c]);
    }
}

// K3: output pass — recompute x, scale/bias (computed in prologue) + ReLU, NT store.
// Reverse tile order to hit backbone tail left in L3 by k1.
__global__ __launch_bounds__(256, 2) void k3_out(const float* __restrict__ bb,
                                                 const int* __restrict__ bidx,
                                                 const float* __restrict__ W,
                                                 const float* __restrict__ gamma,
                                                 const float* __restrict__ beta,
                                                 const float* __restrict__ ws,
                                                 float* __restrict__ out) {
    __shared__ __align__(16) short sW[6 * 3 * 64 * 8];
    __shared__ __align__(16) float sT[NB * STPAD];
    __shared__ __align__(16) float sScale[COCH];
    __shared__ __align__(16) float sBias[COCH];

    stage_W(W, sW);
    for (int i = threadIdx.x; i < NB * COCH; i += blockDim.x)
        sT[(i / COCH) * STPAD + (i % COCH)] = ws[T_OFF + i];
    if (threadIdx.x < COCH) {
        int c = threadIdx.x;
        float mean = ws[GSUM_OFF + c] * (1.f / (float)N_PTS);
        float var  = ws[GSQ_OFF + c] * (1.f / (float)N_PTS) - mean * mean;
        float scl  = gamma[c] * rsqrtf(var + BN_EPS);
        sScale[c] = scl;
        sBias[c]  = beta[c] - mean * scl;
    }
    __syncthreads();

    const int lane = threadIdx.x & 63;
    const int wv = threadIdx.x >> 6;
    const int grp = lane >> 4, lr = lane & 15;

    bf16x8 bf[6][3];
    load_bfrag_lds(sW, lane, bf);

    f32x4 sc[6], bs[6];
    #pragma unroll
    for (int ct = 0; ct < 6; ++ct) {
        sc[ct] = *reinterpret_cast<const f32x4*>(&sScale[ct * 16 + grp * 4]);
        bs[ct] = *reinterpret_cast<const f32x4*>(&sBias[ct * 16 + grp * 4]);
    }

    const int gw = blockIdx.x * 4 + wv;
    for (int t = NT_TILES - 1 - gw; t >= 0; t -= GRID1 * 4) {
        int base = t * 16;
        f32x4 acc[6];
        tile_acc(bb, bidx, sT, bf, base, grp, lr, acc);
        #pragma unroll
        for (int ct = 0; ct < 6; ++ct) {
            f32x4 y;
            #pragma unroll
            for (int r = 0; r < 4; ++r)
                y[r] = fmaxf(acc[ct][r] * sc[ct][r] + bs[ct][r], 0.f);
            __builtin_nontemporal_store(y,
                reinterpret_cast<f32x4*>(out + (size_t)(base + lr) * COCH + ct * 16 + grp * 4));
        }
    }
}

extern "C" void kernel_launch(void* const* d_in, const int* in_sizes, int n_in,
                              void* d_out, int out_size, void* d_ws, size_t ws_size,
                              hipStream_t stream) {
    const float* bb    = (const float*)d_in[0];
    const int*   bidx  = (const int*)d_in[1];
    const float* text  = (const float*)d_in[2];
    const float* W     = (const float*)d_in[3];
    const float* gamma = (const float*)d_in[4];
    const float* beta  = (const float*)d_in[5];
    float* out = (float*)d_out;
    float* ws  = (float*)d_ws;

    hipLaunchKernelGGL(k0_init, dim3(NB + 1), dim3(128), 0, stream, text, W, ws);
    hipLaunchKernelGGL(k1_stats, dim3(GRID1), dim3(256), 0, stream, bb, bidx, W, ws);
    hipLaunchKernelGGL(k3_out, dim3(GRID1), dim3(256), 0, stream, bb, bidx, W, gamma, beta, ws, out);
}